// Round 1
// baseline (10322.500 us; speedup 1.0000x reference)
//
#include <hip/hip_runtime.h>
#include <hip/hip_bf16.h>

#define HID 2048
#define FFN_DIM 7168
#define NE 8
#define NT 8192            // tokens = B*S
#define NR 16384           // rows = NT * TOP_K
#define BK 32
#define LDT 40             // padded LDS leading dim (bf16 elems): 80B = 20-bank stride

typedef __bf16 bf16_t;
using bf16x8 = __attribute__((ext_vector_type(8))) __bf16;
using bf16x4 = __attribute__((ext_vector_type(4))) __bf16;
using floatx4 = __attribute__((ext_vector_type(4))) float;

// ---- workspace layout (bytes) ----
#define OFF_CNT    0        // 8 ints (zeroed by memset)
#define OFF_EOFF   128      // 9 ints
#define OFF_CURSOR 256      // 8 ints
#define OFF_SELE   1024                     // int[NR]
#define OFF_SELW   (OFF_SELE + NR * 4)      // float[NR]
#define OFF_RTOK   (OFF_SELW + NR * 4)      // int[NR]
#define OFF_RW     (OFF_RTOK + NR * 4)      // float[NR]
#define OFF_REXP   (OFF_RW + NR * 4)        // int[NR]
#define OFF_A      331776                   // bf16[NR][HID]   (67.1 MB)
#define OFF_HMID   (OFF_A + (size_t)NR * HID * 2)  // bf16[NR][FFN] (234.9 MB)

// ---------------- router: logits, top-2, counts ----------------
__global__ __launch_bounds__(64) void router_kernel(
    const float* __restrict__ x, const float* __restrict__ gw,
    float* __restrict__ logits_out, int* __restrict__ cnt,
    int* __restrict__ sel_e, float* __restrict__ sel_w)
{
    int t = blockIdx.x;
    int lane = threadIdx.x;
    const float* xr = x + (size_t)t * HID;
    float acc[NE];
#pragma unroll
    for (int e = 0; e < NE; e++) acc[e] = 0.f;
    for (int h = lane; h < HID; h += 64) {
        float xv = xr[h];
#pragma unroll
        for (int e = 0; e < NE; e++) acc[e] += xv * gw[e * HID + h];
    }
#pragma unroll
    for (int e = 0; e < NE; e++) {
#pragma unroll
        for (int off = 32; off > 0; off >>= 1)
            acc[e] += __shfl_down(acc[e], off);
    }
    if (lane == 0) {
#pragma unroll
        for (int e = 0; e < NE; e++) logits_out[t * NE + e] = acc[e];
        int i0 = 0;
#pragma unroll
        for (int e = 1; e < NE; e++) if (acc[e] > acc[i0]) i0 = e;
        int i1 = (i0 == 0) ? 1 : 0;
#pragma unroll
        for (int e = 0; e < NE; e++) if (e != i0 && acc[e] > acc[i1]) i1 = e;
        // softmax over top-2 == softmax-then-renormalize
        float w0 = 1.f / (1.f + __expf(acc[i1] - acc[i0]));
        float w1 = 1.f - w0;
        sel_e[t * 2] = i0; sel_e[t * 2 + 1] = i1;
        sel_w[t * 2] = w0; sel_w[t * 2 + 1] = w1;
        atomicAdd(&cnt[i0], 1);
        atomicAdd(&cnt[i1], 1);
    }
}

__global__ void offsets_kernel(const int* __restrict__ cnt,
                               int* __restrict__ eoff, int* __restrict__ cursor)
{
    int s = 0;
    for (int e = 0; e < NE; e++) { eoff[e] = s; cursor[e] = s; s += cnt[e]; }
    eoff[NE] = s;
}

__global__ __launch_bounds__(256) void scatter_kernel(
    const int* __restrict__ sel_e, const float* __restrict__ sel_w,
    int* __restrict__ cursor, int* __restrict__ rtok,
    float* __restrict__ rw, int* __restrict__ rexp)
{
    int i = blockIdx.x * 256 + threadIdx.x;
    if (i >= NR) return;
    int t = i >> 1;
    int e = sel_e[i];
    float w = sel_w[i];
    int pos = atomicAdd(&cursor[e], 1);
    rtok[pos] = t; rw[pos] = w; rexp[pos] = e;
}

// ---------------- gather: A_all[r][h] = bf16(x[t][h] / scales[e][h]) ----------------
__global__ __launch_bounds__(256) void gather_kernel(
    const float* __restrict__ x, const float* __restrict__ scales,
    const int* __restrict__ rtok, const int* __restrict__ rexp,
    bf16_t* __restrict__ A)
{
    int r = blockIdx.x;
    int t = rtok[r];
    int e = rexp[r];
    const float* xr = x + (size_t)t * HID;
    const float* sr = scales + (size_t)e * HID;
    bf16_t* ar = A + (size_t)r * HID;
    for (int h = threadIdx.x * 4; h < HID; h += 256 * 4) {
        float4 xv = *(const float4*)&xr[h];
        float4 sv = *(const float4*)&sr[h];
        bf16x4 v = { (bf16_t)(xv.x / sv.x), (bf16_t)(xv.y / sv.y),
                     (bf16_t)(xv.z / sv.z), (bf16_t)(xv.w / sv.w) };
        *(bf16x4*)&ar[h] = v;
    }
}

// ---------------- GEMM1: hmid = silu(A w1^T) * (A w3^T), bf16 out ----------------
__global__ __launch_bounds__(256) void gemm1_kernel(
    const bf16_t* __restrict__ A, const float* __restrict__ w1,
    const float* __restrict__ w3, const int* __restrict__ eoff,
    bf16_t* __restrict__ hmid)
{
    int bid = blockIdx.x;
    int mt = bid & 31;              // m fastest: consecutive blocks share B tiles
    int ntile = (bid >> 5) % 56;
    int e = bid / (32 * 56);
    int row0 = eoff[e], row_end = eoff[e + 1];
    int row_base = row0 + mt * 128;
    if (row_base >= row_end) return;
    int n_base = ntile * 128;

    __shared__ bf16_t As[128 * LDT];
    __shared__ bf16_t B1s[128 * LDT];
    __shared__ bf16_t B3s[128 * LDT];

    int tid = threadIdx.x;
    int lane = tid & 63;
    int wv = tid >> 6;
    int wm = wv & 1, wn = wv >> 1;

    const float* w1e = w1 + (size_t)e * FFN_DIM * HID;
    const float* w3e = w3 + (size_t)e * FFN_DIM * HID;

    floatx4 acc1[4][4], acc3[4][4];
#pragma unroll
    for (int i = 0; i < 4; i++)
#pragma unroll
        for (int j = 0; j < 4; j++) {
            acc1[i][j] = (floatx4){0.f, 0.f, 0.f, 0.f};
            acc3[i][j] = (floatx4){0.f, 0.f, 0.f, 0.f};
        }

    int srow = tid >> 1;            // 0..127
    int shalf = (tid & 1) * 16;     // k sub-offset 0 / 16

    for (int k0 = 0; k0 < HID; k0 += BK) {
        __syncthreads();
        // stage A (bf16 copy, zero-pad invalid rows)
        {
            int gr = row_base + srow;
            uint4 v0 = {0, 0, 0, 0}, v1 = {0, 0, 0, 0};
            if (gr < row_end) {
                const bf16_t* src = A + (size_t)gr * HID + k0 + shalf;
                v0 = *(const uint4*)src;
                v1 = *(const uint4*)(src + 8);
            }
            *(uint4*)&As[srow * LDT + shalf] = v0;
            *(uint4*)&As[srow * LDT + shalf + 8] = v1;
        }
        // stage B1/B3 (fp32 -> bf16)
        {
            const float* s1 = w1e + (size_t)(n_base + srow) * HID + k0 + shalf;
            float4 f0 = *(const float4*)s1, f1 = *(const float4*)(s1 + 4);
            float4 f2 = *(const float4*)(s1 + 8), f3 = *(const float4*)(s1 + 12);
            bf16x8 p0 = { (bf16_t)f0.x, (bf16_t)f0.y, (bf16_t)f0.z, (bf16_t)f0.w,
                          (bf16_t)f1.x, (bf16_t)f1.y, (bf16_t)f1.z, (bf16_t)f1.w };
            bf16x8 p1 = { (bf16_t)f2.x, (bf16_t)f2.y, (bf16_t)f2.z, (bf16_t)f2.w,
                          (bf16_t)f3.x, (bf16_t)f3.y, (bf16_t)f3.z, (bf16_t)f3.w };
            *(bf16x8*)&B1s[srow * LDT + shalf] = p0;
            *(bf16x8*)&B1s[srow * LDT + shalf + 8] = p1;
            const float* s3 = w3e + (size_t)(n_base + srow) * HID + k0 + shalf;
            f0 = *(const float4*)s3; f1 = *(const float4*)(s3 + 4);
            f2 = *(const float4*)(s3 + 8); f3 = *(const float4*)(s3 + 12);
            bf16x8 q0 = { (bf16_t)f0.x, (bf16_t)f0.y, (bf16_t)f0.z, (bf16_t)f0.w,
                          (bf16_t)f1.x, (bf16_t)f1.y, (bf16_t)f1.z, (bf16_t)f1.w };
            bf16x8 q1 = { (bf16_t)f2.x, (bf16_t)f2.y, (bf16_t)f2.z, (bf16_t)f2.w,
                          (bf16_t)f3.x, (bf16_t)f3.y, (bf16_t)f3.z, (bf16_t)f3.w };
            *(bf16x8*)&B3s[srow * LDT + shalf] = q0;
            *(bf16x8*)&B3s[srow * LDT + shalf + 8] = q1;
        }
        __syncthreads();

        int kq = (lane >> 4) * 8;
        bf16x8 bf1[4], bf3[4];
#pragma unroll
        for (int in = 0; in < 4; in++) {
            int nrow = wn * 64 + in * 16 + (lane & 15);
            bf1[in] = *(const bf16x8*)&B1s[nrow * LDT + kq];
            bf3[in] = *(const bf16x8*)&B3s[nrow * LDT + kq];
        }
#pragma unroll
        for (int im = 0; im < 4; im++) {
            bf16x8 a = *(const bf16x8*)&As[(wm * 64 + im * 16 + (lane & 15)) * LDT + kq];
#pragma unroll
            for (int in = 0; in < 4; in++) {
                acc1[im][in] = __builtin_amdgcn_mfma_f32_16x16x32_bf16(a, bf1[in], acc1[im][in], 0, 0, 0);
                acc3[im][in] = __builtin_amdgcn_mfma_f32_16x16x32_bf16(a, bf3[in], acc3[im][in], 0, 0, 0);
            }
        }
    }

    // epilogue: silu(acc1)*acc3 -> bf16 hmid
#pragma unroll
    for (int im = 0; im < 4; im++) {
#pragma unroll
        for (int r = 0; r < 4; r++) {
            int m = wm * 64 + im * 16 + (lane >> 4) * 4 + r;
            int gr = row_base + m;
            if (gr < row_end) {
#pragma unroll
                for (int in = 0; in < 4; in++) {
                    int f = n_base + wn * 64 + in * 16 + (lane & 15);
                    float s1 = acc1[im][in][r];
                    float s3 = acc3[im][in][r];
                    float hm = s1 / (1.f + __expf(-s1)) * s3;
                    hmid[(size_t)gr * FFN_DIM + f] = (bf16_t)hm;
                }
            }
        }
    }
}

// ---------------- GEMM2: out[t] += w_r * (hmid_row @ w2^T) ----------------
__global__ __launch_bounds__(256) void gemm2_kernel(
    const bf16_t* __restrict__ hmid, const float* __restrict__ w2,
    const int* __restrict__ eoff, const int* __restrict__ rtok,
    const float* __restrict__ rw, float* __restrict__ out)
{
    int bid = blockIdx.x;
    int mt = bid & 31;
    int ntile = (bid >> 5) & 15;
    int e = bid >> 9;
    int row0 = eoff[e], row_end = eoff[e + 1];
    int row_base = row0 + mt * 128;
    if (row_base >= row_end) return;
    int n_base = ntile * 128;

    __shared__ bf16_t As[128 * LDT];
    __shared__ bf16_t Bs[128 * LDT];

    int tid = threadIdx.x;
    int lane = tid & 63;
    int wv = tid >> 6;
    int wm = wv & 1, wn = wv >> 1;

    const float* w2e = w2 + (size_t)e * HID * FFN_DIM;

    floatx4 acc[4][4];
#pragma unroll
    for (int i = 0; i < 4; i++)
#pragma unroll
        for (int j = 0; j < 4; j++) acc[i][j] = (floatx4){0.f, 0.f, 0.f, 0.f};

    int srow = tid >> 1;
    int shalf = (tid & 1) * 16;

    for (int k0 = 0; k0 < FFN_DIM; k0 += BK) {
        __syncthreads();
        {
            int gr = row_base + srow;
            uint4 v0 = {0, 0, 0, 0}, v1 = {0, 0, 0, 0};
            if (gr < row_end) {
                const bf16_t* src = hmid + (size_t)gr * FFN_DIM + k0 + shalf;
                v0 = *(const uint4*)src;
                v1 = *(const uint4*)(src + 8);
            }
            *(uint4*)&As[srow * LDT + shalf] = v0;
            *(uint4*)&As[srow * LDT + shalf + 8] = v1;
        }
        {
            const float* sB = w2e + (size_t)(n_base + srow) * FFN_DIM + k0 + shalf;
            float4 f0 = *(const float4*)sB, f1 = *(const float4*)(sB + 4);
            float4 f2 = *(const float4*)(sB + 8), f3 = *(const float4*)(sB + 12);
            bf16x8 p0 = { (bf16_t)f0.x, (bf16_t)f0.y, (bf16_t)f0.z, (bf16_t)f0.w,
                          (bf16_t)f1.x, (bf16_t)f1.y, (bf16_t)f1.z, (bf16_t)f1.w };
            bf16x8 p1 = { (bf16_t)f2.x, (bf16_t)f2.y, (bf16_t)f2.z, (bf16_t)f2.w,
                          (bf16_t)f3.x, (bf16_t)f3.y, (bf16_t)f3.z, (bf16_t)f3.w };
            *(bf16x8*)&Bs[srow * LDT + shalf] = p0;
            *(bf16x8*)&Bs[srow * LDT + shalf + 8] = p1;
        }
        __syncthreads();

        int kq = (lane >> 4) * 8;
        bf16x8 bf[4];
#pragma unroll
        for (int in = 0; in < 4; in++)
            bf[in] = *(const bf16x8*)&Bs[(wn * 64 + in * 16 + (lane & 15)) * LDT + kq];
#pragma unroll
        for (int im = 0; im < 4; im++) {
            bf16x8 a = *(const bf16x8*)&As[(wm * 64 + im * 16 + (lane & 15)) * LDT + kq];
#pragma unroll
            for (int in = 0; in < 4; in++)
                acc[im][in] = __builtin_amdgcn_mfma_f32_16x16x32_bf16(a, bf[in], acc[im][in], 0, 0, 0);
        }
    }

#pragma unroll
    for (int im = 0; im < 4; im++) {
#pragma unroll
        for (int r = 0; r < 4; r++) {
            int m = wm * 64 + im * 16 + (lane >> 4) * 4 + r;
            int gr = row_base + m;
            if (gr < row_end) {
                int tkn = rtok[gr];
                float wgt = rw[gr];
#pragma unroll
                for (int in = 0; in < 4; in++) {
                    int h = n_base + wn * 64 + in * 16 + (lane & 15);
                    atomicAdd(&out[(size_t)tkn * HID + h], wgt * acc[im][in][r]);
                }
            }
        }
    }
}

extern "C" void kernel_launch(void* const* d_in, const int* in_sizes, int n_in,
                              void* d_out, int out_size, void* d_ws, size_t ws_size,
                              hipStream_t stream)
{
    const float* x      = (const float*)d_in[0];
    const float* gw     = (const float*)d_in[1];
    const float* w1     = (const float*)d_in[2];
    const float* w3     = (const float*)d_in[3];
    const float* w2     = (const float*)d_in[4];
    const float* scales = (const float*)d_in[5];
    float* out = (float*)d_out;
    float* logits = out + (size_t)NT * HID;

    char* ws = (char*)d_ws;
    int*    cnt    = (int*)(ws + OFF_CNT);
    int*    eoff   = (int*)(ws + OFF_EOFF);
    int*    cursor = (int*)(ws + OFF_CURSOR);
    int*    sel_e  = (int*)(ws + OFF_SELE);
    float*  sel_w  = (float*)(ws + OFF_SELW);
    int*    rtok   = (int*)(ws + OFF_RTOK);
    float*  rwt    = (float*)(ws + OFF_RW);
    int*    rexp   = (int*)(ws + OFF_REXP);
    bf16_t* Abuf   = (bf16_t*)(ws + OFF_A);
    bf16_t* hmid   = (bf16_t*)(ws + OFF_HMID);

    hipMemsetAsync(d_out, 0, (size_t)NT * HID * sizeof(float), stream);
    hipMemsetAsync(ws, 0, 1024, stream);

    router_kernel<<<NT, 64, 0, stream>>>(x, gw, logits, cnt, sel_e, sel_w);
    offsets_kernel<<<1, 1, 0, stream>>>(cnt, eoff, cursor);
    scatter_kernel<<<NR / 256, 256, 0, stream>>>(sel_e, sel_w, cursor, rtok, rwt, rexp);
    gather_kernel<<<NR, 256, 0, stream>>>(x, scales, rtok, rexp, Abuf);
    gemm1_kernel<<<32 * 56 * NE, 256, 0, stream>>>(Abuf, w1, w3, eoff, hmid);
    gemm2_kernel<<<32 * 16 * NE, 256, 0, stream>>>(hmid, w2, eoff, rtok, rwt, out);
}